// Round 10
// baseline (57.173 us; speedup 1.0000x reference)
//
#include <hip/hip_runtime.h>

// KnowledgeConsistentAttention v9 (MI355X / gfx950)
// sumpool3x3(scores)[p,q] = kern[p,:] . G[:,q], G = sumpool3x3(fg)
// => flash attention, K=V=kern (normalized fg cols + eps), Q = G cols, d=64.
//
// v9: BARRIER-FREE main loop. A-fragments (Kp rows) and B-fragments (KB)
// read directly from global (L2-resident, XCD-colocated) -- no LDS staging,
// no __syncthreads until the epilogue. Wave = 64 queries x 256 keys (Q in
// 32 VGPR; 8KB of K feeds 32 MFMA). Block = 4 waves = (b, y, key-quarter).
// 4-way cross-block combine: partials to out/PO + l to LW, reduce kernel.

typedef __bf16 bf16_t;
typedef __bf16 bf16x2 __attribute__((ext_vector_type(2)));
typedef __bf16 bf16x8 __attribute__((ext_vector_type(8)));
typedef float f32x4 __attribute__((ext_vector_type(4)));

#define HW_ 4096
#define CH 64

static __device__ __forceinline__ int pack_bf16x2(float a, float b) {
  bf16x2 p; p[0] = (bf16_t)a; p[1] = (bf16_t)b;
  return __builtin_bit_cast(int, p);
}

// ---------------- prep: kern (2 layouts) + pooled/prescaled Q ----------------
__global__ __launch_bounds__(1024, 1) void kca_prep(const float* __restrict__ fg,
                                                    char* __restrict__ KpB,
                                                    char* __restrict__ KBB,
                                                    char* __restrict__ GtB) {
  const int b = blockIdx.x >> 6, y = blockIdx.x & 63;
  const int t = threadIdx.x;
  const float* F = fg + (size_t)b * (CH * HW_);

  __shared__ float  Ft[3 * 64 * 64];   // [r][c][x] f32, rows y-1..y+1
  __shared__ bf16_t Ks[64 * 72];       // [x][c], stride 72 (144B, 16B-aligned)
  __shared__ bf16_t Gs[64 * 72];
  __shared__ float  red[16][64];
  __shared__ float  rn[64];

#pragma unroll
  for (int k = 0; k < 3; ++k) {
    const int o = t + k * 1024;          // f32x4 index
    const int r = o >> 10, c = (o >> 4) & 63, x4 = o & 15;
    const int gy = y - 1 + r;
    f32x4 v = {0.f, 0.f, 0.f, 0.f};
    if (gy >= 0 && gy <= 63) v = *(const f32x4*)(F + c * HW_ + gy * 64 + x4 * 4);
    *(f32x4*)&Ft[o * 4] = v;
  }
  __syncthreads();

  const int x = t & 63, c0 = t >> 6;     // c0 in 0..15 -> channels 4*c0..+3
  float v4[4], g4[4], ssq = 0.f;
#pragma unroll
  for (int i = 0; i < 4; ++i) {
    const int c = c0 * 4 + i;
    const float v = Ft[4096 + c * 64 + x] + 1e-7f;
    v4[i] = v; ssq = fmaf(v, v, ssq);
    float s = 0.f;
#pragma unroll
    for (int r = 0; r < 3; ++r) {
      const float* row = &Ft[r * 4096 + c * 64];
      float vv = row[x];
      if (x > 0)  vv += row[x - 1];
      if (x < 63) vv += row[x + 1];
      s += vv;
    }
    g4[i] = s * 1.4426950408889634f;     // log2e prescale (exp2-domain softmax)
  }
  red[c0][x] = ssq;
  __syncthreads();
  if (t < 512) red[t >> 6][t & 63] += red[(t >> 6) + 8][t & 63];
  __syncthreads();
  if (t < 256) red[t >> 6][t & 63] += red[(t >> 6) + 4][t & 63];
  __syncthreads();
  if (t < 64) rn[t] = 1.0f / sqrtf(red[0][t] + red[1][t] + red[2][t] + red[3][t]);
  __syncthreads();
  {
    const float rv = rn[x];
    bf16x2* ksp = (bf16x2*)((char*)Ks + x * 144 + c0 * 8);
    bf16x2* gsp = (bf16x2*)((char*)Gs + x * 144 + c0 * 8);
    bf16x2 k0; k0[0] = (bf16_t)(v4[0] * rv); k0[1] = (bf16_t)(v4[1] * rv);
    bf16x2 k1; k1[0] = (bf16_t)(v4[2] * rv); k1[1] = (bf16_t)(v4[3] * rv);
    bf16x2 g0; g0[0] = (bf16_t)g4[0]; g0[1] = (bf16_t)g4[1];
    bf16x2 g1; g1[0] = (bf16_t)g4[2]; g1[1] = (bf16_t)g4[3];
    ksp[0] = k0; ksp[1] = k1;
    gsp[0] = g0; gsp[1] = g1;
  }
  __syncthreads();

  char* Kp_b = KpB + (size_t)b * (HW_ * CH * 2) + (size_t)y * 8192;  // [p][c] 128B rows
  char* Gt_b = GtB + (size_t)b * (HW_ * CH * 2) + (size_t)y * 8192;  // [q][c] 128B rows
  char* KB_b = KBB + (size_t)b * (HW_ * CH * 2);                     // [tile][mt][lane][16B]
  if (t < 512) {
    const int row = t >> 3, colb = (t & 7) * 16;
    *(bf16x8*)(Kp_b + row * 128 + colb) = *(const bf16x8*)((char*)Ks + row * 144 + colb);
    // KB: GEMM2 B-fragment order with slot permutation baked in.
    // lane(l15,lg) word j = kern[tile*32 + 16*(j>>2) + 4*lg + (j&3)][16*mt + l15]
    const int tile = t >> 8;           // 0..1
    const int mt   = (t >> 6) & 3;
    const int ln   = t & 63;
    const int l15_ = ln & 15, lg_ = ln >> 4;
    bf16x8 kv;
#pragma unroll
    for (int j = 0; j < 8; ++j) {
      const int pl = tile * 32 + 16 * (j >> 2) + 4 * lg_ + (j & 3);
      kv[j] = Ks[pl * 72 + 16 * mt + l15_];
    }
    *(bf16x8*)(KB_b + (size_t)(2 * y + tile) * 4096 + mt * 1024 + ln * 16) = kv;
  } else {
    const int s = t - 512;
    const int row = s >> 3, colb = (s & 7) * 16;
    *(bf16x8*)(Gt_b + row * 128 + colb) = *(const bf16x8*)((char*)Gs + row * 144 + colb);
  }
}

// ---------------- main: barrier-free fused flash attention ----------------
__global__ __launch_bounds__(256, 1) void kca_attn(const char* __restrict__ KpB,
                                                   const char* __restrict__ KBB,
                                                   const char* __restrict__ GtB,
                                                   float* __restrict__ out,
                                                   float* __restrict__ po,
                                                   float* __restrict__ lw) {
  // XCD-aware remap over 1024 blocks: each XCD owns 128 contiguous sw ids
  // (= 2 (h,b) slices x 64 y) -> Kp/KB working set L2-resident per XCD.
  const int sw = ((blockIdx.x & 7) << 7) | (blockIdx.x >> 3);
  const int h = sw >> 8;               // key quarter 0..3
  const int b = (sw >> 6) & 3, y = sw & 63;
  const int t = threadIdx.x;
  const int lane = t & 63, w = t >> 6;     // wave 0..3
  const int l15 = lane & 15, lg = lane >> 4;

  const char* Kp_b = KpB + (size_t)b * (HW_ * CH * 2);
  const char* KB_b = KBB + (size_t)b * (HW_ * CH * 2);
  const char* Gt_b = GtB + (size_t)b * (HW_ * CH * 2);

  __shared__ float Rcomb[2][64 * 72];      // epilogue-only combine buffers
  __shared__ float mll[4][64];

  // Q fragments: the wave's entire q-row (64 queries = 4 subtiles), log2e-scaled
  bf16x8 qb[4][2];
#pragma unroll
  for (int qs = 0; qs < 4; ++qs) {
    const char* qr = Gt_b + (size_t)(y * 64 + qs * 16 + l15) * 128 + 16 * lg;
    qb[qs][0] = *(const bf16x8*)qr;
    qb[qs][1] = *(const bf16x8*)(qr + 64);
  }

  f32x4 oaccT[4][4];                       // [qs][mt]: O^T[q=qs*16+4lg+r][c=16mt+l15]
#pragma unroll
  for (int qs = 0; qs < 4; ++qs)
#pragma unroll
    for (int mt = 0; mt < 4; ++mt) { oaccT[qs][mt][0]=0.f; oaccT[qs][mt][1]=0.f; oaccT[qs][mt][2]=0.f; oaccT[qs][mt][3]=0.f; }
  float lpart[4] = {0.f, 0.f, 0.f, 0.f};

  const int pbase = h * 1024 + w * 256;    // this wave's 256 keys
  for (int it = 0; it < 8; ++it) {
    const int p0 = pbase + it * 32;
    // B-fragments: 4 coalesced 1KB wave-loads (L2-resident)
    const char* kbp = KB_b + (size_t)(p0 >> 5) * 4096 + lane * 16;
    const bf16x8 kb0 = *(const bf16x8*)(kbp);
    const bf16x8 kb1 = *(const bf16x8*)(kbp + 1024);
    const bf16x8 kb2 = *(const bf16x8*)(kbp + 2048);
    const bf16x8 kb3 = *(const bf16x8*)(kbp + 3072);

    union PU { int wd[4]; bf16x8 v; } pa[4];

    // GEMM1 + fixed-bias exp2, per 16-key half (f) x 4 q-subtiles
#pragma unroll
    for (int f = 0; f < 2; ++f) {
      const char* ar = Kp_b + (size_t)(p0 + f * 16 + l15) * 128 + 16 * lg;
      const bf16x8 a0 = *(const bf16x8*)(ar);
      const bf16x8 a1 = *(const bf16x8*)(ar + 64);
#pragma unroll
      for (int qs = 0; qs < 4; ++qs) {
        f32x4 z = {0.f, 0.f, 0.f, 0.f};
        z = __builtin_amdgcn_mfma_f32_16x16x32_bf16(a0, qb[qs][0], z, 0, 0, 0);
        z = __builtin_amdgcn_mfma_f32_16x16x32_bf16(a1, qb[qs][1], z, 0, 0, 0);
        const float e0 = exp2f(z[0]), e1 = exp2f(z[1]);
        const float e2 = exp2f(z[2]), e3 = exp2f(z[3]);
        lpart[qs] += (e0 + e1) + (e2 + e3);
        pa[qs].wd[2 * f + 0] = pack_bf16x2(e0, e1);
        pa[qs].wd[2 * f + 1] = pack_bf16x2(e2, e3);
      }
    }

    // GEMM2 (swapped): O^T[q][c] += P . kern
#pragma unroll
    for (int qs = 0; qs < 4; ++qs) {
      oaccT[qs][0] = __builtin_amdgcn_mfma_f32_16x16x32_bf16(pa[qs].v, kb0, oaccT[qs][0], 0, 0, 0);
      oaccT[qs][1] = __builtin_amdgcn_mfma_f32_16x16x32_bf16(pa[qs].v, kb1, oaccT[qs][1], 0, 0, 0);
      oaccT[qs][2] = __builtin_amdgcn_mfma_f32_16x16x32_bf16(pa[qs].v, kb2, oaccT[qs][2], 0, 0, 0);
      oaccT[qs][3] = __builtin_amdgcn_mfma_f32_16x16x32_bf16(pa[qs].v, kb3, oaccT[qs][3], 0, 0, 0);
    }
  }

  // ---- epilogue: combine the block's 4 wave-partials ----
#pragma unroll
  for (int qs = 0; qs < 4; ++qs) {
    lpart[qs] += __shfl_xor(lpart[qs], 16);
    lpart[qs] += __shfl_xor(lpart[qs], 32);
  }
  if (lg == 0) {
#pragma unroll
    for (int qs = 0; qs < 4; ++qs) mll[w][qs * 16 + l15] = lpart[qs];
  }
  float* Rg = &Rcomb[w & 1][0];
  if (w < 2) {
#pragma unroll
    for (int qs = 0; qs < 4; ++qs)
#pragma unroll
      for (int mt = 0; mt < 4; ++mt)
#pragma unroll
        for (int r = 0; r < 4; ++r)
          Rg[(16 * mt + l15) * 72 + qs * 16 + 4 * lg + r] = oaccT[qs][mt][r];
  }
  __syncthreads();
  if (w >= 2) {
#pragma unroll
    for (int qs = 0; qs < 4; ++qs)
#pragma unroll
      for (int mt = 0; mt < 4; ++mt)
#pragma unroll
        for (int r = 0; r < 4; ++r)
          Rg[(16 * mt + l15) * 72 + qs * 16 + 4 * lg + r] += oaccT[qs][mt][r];
  }
  __syncthreads();
  if (t < 64) {
    const float L = mll[0][t] + mll[1][t] + mll[2][t] + mll[3][t];
    lw[(size_t)h * 16384 + (size_t)(b * 64 + y) * 64 + t] = L;
  }
  {
    const int c = t >> 2, q16 = (t & 3) * 16;
    float* dst = (h ? po + (size_t)(h - 1) * 4 * CH * HW_ : out)
               + (size_t)b * CH * HW_ + (size_t)c * HW_ + y * 64 + q16;
    const float* r0 = &Rcomb[0][c * 72 + q16];
    const float* r1 = &Rcomb[1][c * 72 + q16];
#pragma unroll
    for (int j = 0; j < 4; ++j) {
      f32x4 v = *(const f32x4*)(r0 + 4 * j);
      v += *(const f32x4*)(r1 + 4 * j);
      *(f32x4*)(dst + 4 * j) = v;                      // raw quarter-partial
    }
  }
}

// ---------------- reduce: out = sum_h P_h / sum_h l_h, in place ----------------
__global__ __launch_bounds__(256, 8) void kca_reduce(float* __restrict__ out,
                                                     const float* __restrict__ po,
                                                     const float* __restrict__ lw) {
  const size_t idx = ((size_t)blockIdx.x * 256 + threadIdx.x) * 4;  // f32 idx, q%4==0
  const int b = (int)(idx >> 18);
  const int y = (int)((idx >> 6) & 63);
  const int q = (int)(idx & 63);
  const size_t lidx = (size_t)(b * 64 + y) * 64 + q;
  f32x4 v = *(const f32x4*)(out + idx);
  v += *(const f32x4*)(po + idx);
  v += *(const f32x4*)(po + 1048576 + idx);
  v += *(const f32x4*)(po + 2097152 + idx);
  f32x4 l = *(const f32x4*)(lw + lidx);
  l += *(const f32x4*)(lw + 16384 + lidx);
  l += *(const f32x4*)(lw + 32768 + lidx);
  l += *(const f32x4*)(lw + 49152 + lidx);
  f32x4 o;
#pragma unroll
  for (int j = 0; j < 4; ++j) o[j] = v[j] * (1.0f / l[j]);
  *(f32x4*)(out + idx) = o;
}

extern "C" void kernel_launch(void* const* d_in, const int* in_sizes, int n_in,
                              void* d_out, int out_size, void* d_ws, size_t ws_size,
                              hipStream_t stream) {
  const float* fg = (const float*)d_in[0];
  float* out = (float*)d_out;
  char* ws = (char*)d_ws;
  char* Kp  = ws;                    // 2 MB  [b][p][c] bf16, linear (A-side kern)
  char* KB  = ws + (2u << 20);       // 2 MB  [b][tile][mt][lane][16B] (B-side kern)
  char* Gt  = ws + (4u << 20);       // 2 MB  [b][q][c] bf16 (pooled Q, log2e-scaled)
  float* PO = (float*)(ws + (6u << 20));    // 12 MB: quarter partials h=1..3
  float* LW = (float*)(ws + (18u << 20));   // 256 KB: [h][b][y][64] l sums
  hipLaunchKernelGGL(kca_prep, dim3(256), dim3(1024), 0, stream, fg, Kp, KB, Gt);
  hipLaunchKernelGGL(kca_attn, dim3(1024), dim3(256), 0, stream, Kp, KB, Gt, out, PO, LW);
  hipLaunchKernelGGL(kca_reduce, dim3(1024), dim3(256), 0, stream, out, PO, LW);
}